// Round 12
// baseline (3355.349 us; speedup 1.0000x reference)
//
#include <hip/hip_runtime.h>
#include <math.h>

#define B_   512
#define T_   2048
#define H_   64
#define NS_  32
#define HH_  128   // 2H
#define G4_  256   // 4H
#define EPSF 1e-5f

typedef _Float16 half8 __attribute__((ext_vector_type(8)));
typedef _Float16 h4   __attribute__((ext_vector_type(4)));
typedef float    f32x4 __attribute__((ext_vector_type(4)));

__device__ __forceinline__ float gelu_f(float x) {
    return 0.5f * x * (1.0f + erff(x * 0.70710678118654752440f));
}
__device__ __forceinline__ float sigmoid_f(float x) {
    return 1.0f / (1.0f + __expf(-x));
}
__device__ __forceinline__ float tanh_f(float x) {
    return 1.0f - 2.0f / (__expf(2.0f * x) + 1.0f);
}

// ---------------------------------------------------------------------------
// Input projection -> packed fp16 x-sequence  seqh[B][T][64]
// ---------------------------------------------------------------------------
__global__ void __launch_bounds__(256) inproj_kernel(
    const float* __restrict__ sensors, const float* __restrict__ W1,
    const float* __restrict__ b1, const float* __restrict__ g1,
    const float* __restrict__ bb1, const float* __restrict__ W2,
    const float* __restrict__ b2, _Float16* __restrict__ seqh)
{
    __shared__ __align__(16) float W1l[NS_ * H_];
    __shared__ __align__(16) float W2l[H_ * H_];
    __shared__ float p1[H_], p2[H_], p3[H_], p4[H_];
    const int tid = threadIdx.x;
    {
        const float4* s1 = (const float4*)W1;
        float4* d1 = (float4*)W1l;
        for (int i = tid; i < NS_ * H_ / 4; i += 256) d1[i] = s1[i];
        const float4* s2 = (const float4*)W2;
        float4* d2 = (float4*)W2l;
        for (int i = tid; i < H_ * H_ / 4; i += 256) d2[i] = s2[i];
        if (tid < H_) { p1[tid] = b1[tid]; p2[tid] = g1[tid];
                        p3[tid] = bb1[tid]; p4[tid] = b2[tid]; }
    }
    __syncthreads();

    const long idx = (long)blockIdx.x * 256 + tid;
    const float* srow = sensors + idx * NS_;
    float sv[NS_];
    #pragma unroll
    for (int q = 0; q < NS_ / 4; ++q) {
        float4 v = *(const float4*)&srow[q * 4];
        sv[q*4+0] = v.x; sv[q*4+1] = v.y; sv[q*4+2] = v.z; sv[q*4+3] = v.w;
    }
    float t1[H_];
    #pragma unroll
    for (int jb = 0; jb < H_ / 4; ++jb) {
        float ax = p1[jb*4+0], ay = p1[jb*4+1], az = p1[jb*4+2], aw = p1[jb*4+3];
        #pragma unroll
        for (int k = 0; k < NS_; ++k) {
            float4 w = *(const float4*)&W1l[k * H_ + jb * 4];
            ax += sv[k]*w.x; ay += sv[k]*w.y; az += sv[k]*w.z; aw += sv[k]*w.w;
        }
        t1[jb*4+0] = ax; t1[jb*4+1] = ay; t1[jb*4+2] = az; t1[jb*4+3] = aw;
    }
    float mean = 0.f;
    #pragma unroll
    for (int j = 0; j < H_; ++j) mean += t1[j];
    mean *= (1.0f / H_);
    float var = 0.f;
    #pragma unroll
    for (int j = 0; j < H_; ++j) { float d = t1[j] - mean; var += d * d; }
    var *= (1.0f / H_);
    const float inv = rsqrtf(var + EPSF);
    #pragma unroll
    for (int j = 0; j < H_; ++j) {
        float nv = (t1[j] - mean) * inv * p2[j] + p3[j];
        t1[j] = gelu_f(nv);
    }
    _Float16* orow = seqh + idx * H_;
    for (int ob = 0; ob < H_ / 4; ++ob) {
        float ax = p4[ob*4+0], ay = p4[ob*4+1];
        float az = p4[ob*4+2], aw = p4[ob*4+3];
        #pragma unroll
        for (int j = 0; j < H_; ++j) {
            float4 w = *(const float4*)&W2l[j * H_ + ob * 4];
            ax += t1[j]*w.x; ay += t1[j]*w.y; az += t1[j]*w.z; aw += t1[j]*w.w;
        }
        h4 o; o[0] = (_Float16)ax; o[1] = (_Float16)ay;
              o[2] = (_Float16)az; o[3] = (_Float16)aw;
        *(h4*)&orow[ob * 4] = o;
    }
}

// ---------------------------------------------------------------------------
// Fused 4-layer pipelined LSTM via MFMA (16x16x32 f16, fp32 accum).
// 256 blocks x 1024 thr = 16 waves; wave (l = wv>>2, gate q = wv&3) owns
// cols [q*64, q*64+64): wf[4][4] = 64 weight VGPRs -> fits 128-reg class,
// no AGPR shuttle. Two-phase step, 2 barriers.
//   gbuf[l][row][gate][u] fp32: phase-1 writes stride-1 (16 lanes), phase-2
//   reads stride-1 (64 lanes, 2-way alias = free) -> no 4-way conflicts.
//   x staged through 8-step double-buffered LDS ring (reg-staged
//   global_load_dwordx4 once per 8 steps, one chunk ahead); layer-0
//   A-fragments read the ring directly.
//   h3 written to 8-step LDS ring by phase 2; waves 14/15 flush one chunk
//   per 8 steps with b128 read + dwordx4 store.
// ---------------------------------------------------------------------------
__global__ void __launch_bounds__(1024, 4) lstm_fused_kernel(
    const float* __restrict__ Wg, const float* __restrict__ bg,
    const _Float16* __restrict__ xin,   // [B][T][64] fp16
    _Float16* __restrict__ h3out)       // [B][T][64] fp16
{
    __shared__ __align__(16) _Float16 combh[4][2][HH_];      // 2 KB
    __shared__ __align__(16) float    gbuf[4][2][4][H_];     // 8 KB
    __shared__ __align__(16) _Float16 xring[2][2][8][H_];    // 4 KB
    __shared__ __align__(16) _Float16 hring[2][2][8][H_];    // 4 KB

    const int tid  = threadIdx.x;
    const int wv   = tid >> 6;
    const int lane = tid & 63;
    const int l    = wv >> 2;               // layer
    const int q    = wv & 3;                // gate (i,f,g,o)
    const int L    = lane & 15;
    const int kgrp = lane >> 4;
    const int arow = lane & 1;              // A broadcast row

    // ---- weight B-fragments: 4 kt x 4 nt, cols q*64 + nt*16 + L ----
    const float* W = Wg + (size_t)l * HH_ * G4_;
    half8 wf[4][4];
    #pragma unroll
    for (int kt = 0; kt < 4; ++kt) {
        #pragma unroll
        for (int nt = 0; nt < 4; ++nt) {
            half8 f;
            #pragma unroll
            for (int j = 0; j < 8; ++j)
                f[j] = (_Float16)W[(kt * 32 + kgrp * 8 + j) * G4_
                                   + q * 64 + nt * 16 + L];
            wf[kt][nt] = f;
        }
    }
    float ba[4];
    #pragma unroll
    for (int nt = 0; nt < 4; ++nt)
        ba[nt] = bg[l * G4_ + q * 64 + nt * 16 + L];

    // nonlin duty (tid < 512): cell (nl_l, nrow, u)
    const bool nlw  = tid < 512;
    const int  nl_l = tid >> 7;
    const int  nrow = (tid >> 6) & 1;
    const int  u    = tid & 63;

    // chunk lane map (shared by x-load and h3-flush duties)
    const int xt  = lane >> 3;
    const int xu8 = (lane & 7) * 8;

    // x duty: waves 0 (row 0) and 1 (row 1)
    const bool xw   = (wv < 2);
    const int  xrow = wv & 1;
    const _Float16* xsrc =
        xin + ((long)(blockIdx.x * 2 + xrow)) * T_ * H_ + xt * H_ + xu8;

    // h3 flush duty: waves 14 (row 0) and 15 (row 1)
    const bool hw   = (wv >= 14);
    const int  hrow = hw ? (wv - 14) : 0;
    _Float16* hdst =
        h3out + ((long)(blockIdx.x * 2 + hrow)) * T_ * H_ + xt * H_ + xu8;

    // ---- init ----
    if (tid < 512) ((float*)combh)[tid] = 0.f;   // zero comb (h(-1)=0)
    half8 xreg = {};
    if (xw) xreg = *(const half8*)xsrc;          // chunk 0
    __syncthreads();
    if (xw) {
        *(half8*)&xring[0][xrow][xt][xu8] = xreg;        // chunk 0 -> parity 0
        xreg = *(const half8*)(xsrc + 8 * H_);           // chunk 1
    }
    __syncthreads();

    float c_reg = 0.f;

    for (int s = 0; s < T_ + 3; ++s) {
        // ---- once-per-8-step duties (top of step, disjoint ring parities) --
        if (xw && (s & 7) == 0) {
            const int c = s >> 3;
            if (c + 1 < T_ / 8)
                *(half8*)&xring[(c + 1) & 1][xrow][xt][xu8] = xreg;
            if (c + 2 < T_ / 8)
                xreg = *(const half8*)(xsrc + (long)(c + 2) * 8 * H_);
        }
        if (hw && s >= 11 && ((s - 3) & 7) == 0) {
            const int cp = ((s - 3) >> 3) - 1;
            half8 v = *(const half8*)&hring[cp & 1][hrow][xt][xu8];
            *(half8*)(hdst + (long)cp * 8 * H_) = v;
        }

        // ---- phase 1: gate matmul ----
        const bool mact = (s >= l) && (s - l < T_);
        if (mact) {
            const _Float16* px = (l == 0)
                ? &xring[(s >> 3) & 1][arow][s & 7][0]
                : &combh[l][arow][0];
            const _Float16* ph = &combh[l][arow][64];
            half8 af0 = *(const half8*)(px + kgrp * 8);
            half8 af1 = *(const half8*)(px + 32 + kgrp * 8);
            half8 af2 = *(const half8*)(ph + kgrp * 8);
            half8 af3 = *(const half8*)(ph + 32 + kgrp * 8);

            f32x4 acc[4];
            #pragma unroll
            for (int nt = 0; nt < 4; ++nt)
                acc[nt] = (f32x4){ba[nt], ba[nt], ba[nt], ba[nt]};
            #pragma unroll
            for (int nt = 0; nt < 4; ++nt) {
                acc[nt] = __builtin_amdgcn_mfma_f32_16x16x32_f16(af0, wf[0][nt], acc[nt], 0, 0, 0);
                acc[nt] = __builtin_amdgcn_mfma_f32_16x16x32_f16(af1, wf[1][nt], acc[nt], 0, 0, 0);
                acc[nt] = __builtin_amdgcn_mfma_f32_16x16x32_f16(af2, wf[2][nt], acc[nt], 0, 0, 0);
                acc[nt] = __builtin_amdgcn_mfma_f32_16x16x32_f16(af3, wf[3][nt], acc[nt], 0, 0, 0);
            }
            if (lane < 16) {                 // D rows 0,1 = regs 0,1 (m89 map)
                #pragma unroll
                for (int nt = 0; nt < 4; ++nt) {
                    gbuf[l][0][q][nt * 16 + L] = acc[nt][0];
                    gbuf[l][1][q][nt * 16 + L] = acc[nt][1];
                }
            }
        }
        __syncthreads();

        // ---- phase 2: nonlinearity ----
        if (nlw) {
            const bool nact = (s >= nl_l) && (s - nl_l < T_);
            if (nact) {
                const int t = s - nl_l;
                const float gi = gbuf[nl_l][nrow][0][u];
                const float gf = gbuf[nl_l][nrow][1][u];
                const float gg = gbuf[nl_l][nrow][2][u];
                const float go = gbuf[nl_l][nrow][3][u];
                c_reg = sigmoid_f(gf) * c_reg + sigmoid_f(gi) * tanh_f(gg);
                const float hn = sigmoid_f(go) * tanh_f(c_reg);
                const _Float16 hh = (_Float16)hn;
                combh[nl_l][nrow][64 + u] = hh;                  // own h(t)
                if (nl_l < 3) combh[nl_l + 1][nrow][u] = hh;     // x_{l+1}(t)
                else hring[(t >> 3) & 1][nrow][t & 7][u] = hh;   // h3 -> ring
            }
        }
        __syncthreads();
    }

    // tail: flush last h3 chunk (t = 2040..2047, parity 1)
    if (hw) {
        const int cp = T_ / 8 - 1;
        half8 v = *(const half8*)&hring[cp & 1][hrow][xt][xu8];
        *(half8*)(hdst + (long)cp * 8 * H_) = v;
    }
}

// ---------------------------------------------------------------------------
// Output projection: y = GELU(LN(h3) @ W_out1 + b_out1) @ W_out2 + b_out2
// ---------------------------------------------------------------------------
__global__ void __launch_bounds__(256) outproj_kernel(
    const _Float16* __restrict__ h16,
    const float* __restrict__ g2, const float* __restrict__ b2,
    const float* __restrict__ W1, const float* __restrict__ b1,
    const float* __restrict__ W2, const float* __restrict__ b2o,
    float* __restrict__ y)
{
    __shared__ __align__(16) float W1l[H_ * H_];
    __shared__ __align__(16) float W2l[H_ * 4];
    __shared__ float pg[H_], pb[H_], pb1[H_];
    const int tid = threadIdx.x;
    {
        const float4* s1 = (const float4*)W1;
        float4* d1 = (float4*)W1l;
        for (int i = tid; i < H_ * H_ / 4; i += 256) d1[i] = s1[i];
        if (tid < H_) {
            pg[tid] = g2[tid]; pb[tid] = b2[tid]; pb1[tid] = b1[tid];
            float4 w; w.x = W2[tid*3+0]; w.y = W2[tid*3+1]; w.z = W2[tid*3+2]; w.w = 0.f;
            *(float4*)&W2l[tid * 4] = w;
        }
    }
    __syncthreads();

    const long idx = (long)blockIdx.x * 256 + tid;
    const _Float16* hrow = h16 + idx * H_;
    float hv[H_];
    #pragma unroll
    for (int q = 0; q < H_ / 8; ++q) {
        half8 v = *(const half8*)&hrow[q * 8];
        #pragma unroll
        for (int j = 0; j < 8; ++j) hv[q*8+j] = (float)v[j];
    }
    float mean = 0.f;
    #pragma unroll
    for (int j = 0; j < H_; ++j) mean += hv[j];
    mean *= (1.0f / H_);
    float var = 0.f;
    #pragma unroll
    for (int j = 0; j < H_; ++j) { float dd = hv[j] - mean; var += dd * dd; }
    var *= (1.0f / H_);
    const float inv = rsqrtf(var + EPSF);
    #pragma unroll
    for (int j = 0; j < H_; ++j) hv[j] = (hv[j] - mean) * inv * pg[j] + pb[j];

    float y0 = b2o[0], y1 = b2o[1], y2 = b2o[2];
    for (int ob = 0; ob < H_ / 4; ++ob) {
        float ax = pb1[ob*4+0], ay = pb1[ob*4+1];
        float az = pb1[ob*4+2], aw = pb1[ob*4+3];
        #pragma unroll
        for (int j = 0; j < H_; ++j) {
            float4 w = *(const float4*)&W1l[j * H_ + ob * 4];
            ax += hv[j]*w.x; ay += hv[j]*w.y; az += hv[j]*w.z; aw += hv[j]*w.w;
        }
        ax = gelu_f(ax); ay = gelu_f(ay); az = gelu_f(az); aw = gelu_f(aw);
        float4 wa = *(const float4*)&W2l[(ob*4+0) * 4];
        float4 wb = *(const float4*)&W2l[(ob*4+1) * 4];
        float4 wc = *(const float4*)&W2l[(ob*4+2) * 4];
        float4 wd = *(const float4*)&W2l[(ob*4+3) * 4];
        y0 += ax*wa.x + ay*wb.x + az*wc.x + aw*wd.x;
        y1 += ax*wa.y + ay*wb.y + az*wc.y + aw*wd.y;
        y2 += ax*wa.z + ay*wb.z + az*wc.z + aw*wd.z;
    }
    y[idx * 3 + 0] = y0;
    y[idx * 3 + 1] = y1;
    y[idx * 3 + 2] = y2;
}

// ---------------------------------------------------------------------------
extern "C" void kernel_launch(void* const* d_in, const int* in_sizes, int n_in,
                              void* d_out, int out_size, void* d_ws, size_t ws_size,
                              hipStream_t stream)
{
    const float* sensors = (const float*)d_in[0];
    const float* W_in1   = (const float*)d_in[1];
    const float* b_in1   = (const float*)d_in[2];
    const float* ln1_g   = (const float*)d_in[3];
    const float* ln1_b   = (const float*)d_in[4];
    const float* W_in2   = (const float*)d_in[5];
    const float* b_in2   = (const float*)d_in[6];
    const float* Wg      = (const float*)d_in[7];
    const float* bg      = (const float*)d_in[8];
    const float* ln2_g   = (const float*)d_in[9];
    const float* ln2_b   = (const float*)d_in[10];
    const float* W_out1  = (const float*)d_in[11];
    const float* b_out1  = (const float*)d_in[12];
    const float* W_out2  = (const float*)d_in[13];
    const float* b_out2  = (const float*)d_in[14];
    float* y = (float*)d_out;

    const size_t elems = (size_t)B_ * T_ * H_;
    _Float16* seqh = (_Float16*)d_ws;                        // 128 MB x (fp16)
    _Float16* h3   = (_Float16*)((char*)d_ws + elems * 2);   // 128 MB h3 (fp16)

    inproj_kernel<<<B_ * T_ / 256, 256, 0, stream>>>(
        sensors, W_in1, b_in1, ln1_g, ln1_b, W_in2, b_in2, seqh);
    lstm_fused_kernel<<<B_ / 2, 1024, 0, stream>>>(Wg, bg, seqh, h3);
    outproj_kernel<<<B_ * T_ / 256, 256, 0, stream>>>(
        h3, ln2_g, ln2_b, W_out1, b_out1, W_out2, b_out2, y);
}